// Round 3
// baseline (3679.960 us; speedup 1.0000x reference)
//
#include <hip/hip_runtime.h>
#include <cstdint>

// ---------------------------------------------------------------------------
// QLoRABigNet. Split-bf16 fp32-grade GEMM expressed as ONE K-concat bf16 GEMM:
//   KC = 3*1088: X-chunks [xh|xh|xl] (per-step source map), W = [wh|wl|wh].
// GEMM: 256x256 tile, BK=64, 512 thr / 8 waves, 8-phase counted-vmcnt schedule
// (m201 template), slot-XOR LDS swizzle, global_load_lds(16B).
// LoRA via K-augmentation cols [1024:1056); t = xh @ [Ah|Al]^T (t_k).
// ---------------------------------------------------------------------------

#define NTOK 16384
#define DIM  1024
#define KP   1088                 // one chunk (1024 + 32 lora + 32 pad)
#define KX   2176                 // act storage: [xh | xl]
#define KC   3264                 // W storage: [wh | wl | wh]
#define NSTEP 51                  // KC / 64
#define RLORA 32
#define NLIN 18
#define NBLK 6

typedef unsigned short u16;
typedef __attribute__((ext_vector_type(8))) short short8;
typedef __attribute__((ext_vector_type(4))) float f32x4;

__device__ __forceinline__ u16 f2bf(float f) {
  uint32_t u = __float_as_uint(f);
  u += 0x7fffu + ((u >> 16) & 1u);
  return (u16)(u >> 16);
}
__device__ __forceinline__ float bf2f(u16 h) {
  return __uint_as_float(((uint32_t)h) << 16);
}
__device__ __forceinline__ void split_bf(float f, u16& h, u16& l) {
  h = f2bf(f);
  l = f2bf(f - bf2f(h));
}
__device__ __forceinline__ void gld16(const void* g, void* lds) {
  __builtin_amdgcn_global_load_lds(
      (const __attribute__((address_space(1))) uint32_t*)g,
      (__attribute__((address_space(3))) uint32_t*)lds, 16, 0, 0);
}

// ---------------------------------------------------------------------------
// pack_w: one layer -> Wcat rows of 3264:
// [wh(1024)|Bh(32)|0(32) | wl(1024)|Bl(32)|0(32) | wh(1024)|Bh(32)|0(32)]
// ---------------------------------------------------------------------------
__global__ void pack_w_k(const int* __restrict__ qw, const float* __restrict__ sc,
                         const float* __restrict__ lb, u16* __restrict__ Wc) {
  const int idx = blockIdx.x * 256 + threadIdx.x;
  if (idx >= 1024 * (KC / 16)) return;
  const int c = idx % (KC / 16);
  const int o = idx / (KC / 16);
  int kind = 4, g = 0;  // 0: w-hi, 1: w-lo, 2: B-hi, 3: B-lo, 4: zero
  if      (c < 64)  { kind = 0; g = c; }
  else if (c < 66)  { kind = 2; g = c - 64; }
  else if (c < 68)  { kind = 4; }
  else if (c < 132) { kind = 1; g = c - 68; }
  else if (c < 134) { kind = 3; g = c - 132; }
  else if (c < 136) { kind = 4; }
  else if (c < 200) { kind = 0; g = c - 136; }
  else if (c < 202) { kind = 2; g = c - 200; }
  u16 out[16];
  if (kind == 0 || kind == 1) {
    const int* q = qw + (size_t)o * 1024 + g * 16;
    const float s = sc[(size_t)o * 64 + g];
#pragma unroll
    for (int j = 0; j < 16; ++j) {
      float w = ((float)q[j] * (2.0f / 15.0f) - 1.0f) * s;
      u16 h, l; split_bf(w, h, l);
      out[j] = (kind == 0) ? h : l;
    }
  } else if (kind == 2 || kind == 3) {
    const float* B = lb + (size_t)o * RLORA + g * 16;
#pragma unroll
    for (int j = 0; j < 16; ++j) {
      u16 h, l; split_bf(B[j], h, l);
      out[j] = (kind == 2) ? h : l;
    }
  } else {
#pragma unroll
    for (int j = 0; j < 16; ++j) out[j] = 0;
  }
  u16* w = Wc + (size_t)o * KC + c * 16;
#pragma unroll
  for (int j = 0; j < 16; ++j) w[j] = out[j];
}

// Acat[li][r]: [Ah(1024)|0(64) | Al(1024)|0(64)]  (stride KX)
__global__ void pack_a_k(const float* __restrict__ la, u16* __restrict__ Ac) {
  const int idx = blockIdx.x * 256 + threadIdx.x;
  if (idx >= NLIN * RLORA * (KX / 16)) return;
  const int c = idx % (KX / 16);
  const int rr = idx / (KX / 16);        // li*32 + r
  u16 out[16];
  int kind = 2, g = 0;
  if (c < 64) { kind = 0; g = c; }
  else if (c >= 68 && c < 132) { kind = 1; g = c - 68; }
  if (kind < 2) {
    const float* a = la + (size_t)rr * 1024 + g * 16;
#pragma unroll
    for (int j = 0; j < 16; ++j) {
      u16 h, l; split_bf(a[j], h, l);
      out[j] = (kind == 0) ? h : l;
    }
  } else {
#pragma unroll
    for (int j = 0; j < 16; ++j) out[j] = 0;
  }
  u16* p = Ac + (size_t)rr * KX + c * 16;
#pragma unroll
  for (int j = 0; j < 16; ++j) p[j] = out[j];
}

// acts: [xh(1024)|pad(64) | xl(1024)|pad(64)]; pads of BOTH buffers zeroed.
__global__ void pack_x_k(const float* __restrict__ x,
                         u16* __restrict__ aA, u16* __restrict__ aB) {
  const int idx = blockIdx.x * 256 + threadIdx.x;
  if (idx >= NTOK * 68) return;          // 68 chunks: 64 data + 4 pad
  const int c = idx % 68;
  const int n = idx / 68;
  const size_t base = (size_t)n * KX;
  if (c < 64) {
    const float* xp = x + (size_t)n * DIM + c * 16;
#pragma unroll
    for (int j = 0; j < 16; ++j) {
      u16 h, l; split_bf(xp[j], h, l);
      aA[base + c * 16 + j] = h;
      aA[base + KP + c * 16 + j] = l;
    }
  } else {
#pragma unroll
    for (int j = 0; j < 16; ++j) {
      aA[base + c * 16 + j] = 0;      aA[base + KP + c * 16 + j] = 0;
      aB[base + c * 16 + j] = 0;      aB[base + KP + c * 16 + j] = 0;
    }
  }
}

// ---------------------------------------------------------------------------
// t_k: t = xh @ [Ah|Al]^T -> X h-cols [1024:1056). 128 rows/block, 4 waves.
// Double-buffered staging, counted vmcnt(4).
// ---------------------------------------------------------------------------
__global__ __launch_bounds__(256, 4) void t_k(
    u16* __restrict__ X, const u16* __restrict__ Ac) {
  __shared__ __align__(16) u16 sX[2][128 * 64];
  const int tid = threadIdx.x, lane = tid & 63, wave = tid >> 6;
  const int row0 = blockIdx.x * 128;
  const int srow = tid >> 3;
  const int lslot = ((tid & 7) ^ (srow & 7)) * 8;
  const int fr = lane & 15, sl = lane >> 4, sx = lane & 7;

  f32x4 acc[2][2];
#pragma unroll
  for (int i = 0; i < 2; ++i)
#pragma unroll
    for (int j = 0; j < 2; ++j) acc[i][j] = {0.f, 0.f, 0.f, 0.f};

  auto stage = [&](int buf, int s) {
    const int xb = (s < 17 ? s : s - 17) * 64;   // both halves read xh
#pragma unroll
    for (int i = 0; i < 4; ++i)
      gld16(X + (size_t)(row0 + i * 32 + srow) * KX + xb + lslot,
            &sX[buf][i * 2048 + wave * 512]);
  };
  stage(0, 0);
  for (int t = 0; t < 34; ++t) {
    const int c = t & 1;
    if (t + 1 < 34) {
      stage(c ^ 1, t + 1);
      asm volatile("s_waitcnt vmcnt(4)" ::: "memory");
    } else {
      asm volatile("s_waitcnt vmcnt(0)" ::: "memory");
    }
    __builtin_amdgcn_s_barrier();
    short8 av[2][2], bv[2][2];
#pragma unroll
    for (int mi = 0; mi < 2; ++mi)
#pragma unroll
      for (int kk = 0; kk < 2; ++kk) {
        const int row = wave * 32 + mi * 16 + fr;
        av[mi][kk] = *(const short8*)&sX[c][row * 64 + (((kk * 4 + sl) ^ sx)) * 8];
      }
#pragma unroll
    for (int ni = 0; ni < 2; ++ni)
#pragma unroll
      for (int kk = 0; kk < 2; ++kk) {
        const int ar = ni * 16 + fr;
        bv[ni][kk] = *(const short8*)&Ac[(size_t)ar * KX + t * 64 + kk * 32 + sl * 8];
      }
#pragma unroll
    for (int mi = 0; mi < 2; ++mi)
#pragma unroll
      for (int ni = 0; ni < 2; ++ni)
#pragma unroll
        for (int kk = 0; kk < 2; ++kk)
          acc[mi][ni] = __builtin_amdgcn_mfma_f32_16x16x32_bf16(
              av[mi][kk], bv[ni][kk], acc[mi][ni], 0, 0, 0);
    __builtin_amdgcn_s_barrier();
  }
  const int crow0 = row0 + wave * 32 + (lane >> 4) * 4;
#pragma unroll
  for (int ni = 0; ni < 2; ++ni) {
    const int col = DIM + ni * 16 + fr;
#pragma unroll
    for (int mi = 0; mi < 2; ++mi)
#pragma unroll
      for (int r = 0; r < 4; ++r)
        X[(size_t)(crow0 + mi * 16 + r) * KX + col] = f2bf(acc[mi][ni][r]);
  }
}

// ---------------------------------------------------------------------------
// Main GEMM: 256x256 tile, 8-phase counted-vmcnt schedule over NSTEP=51.
// MODE 0: relu -> split act out (stride KX). MODE 1: +resid -> fp32 out.
// ---------------------------------------------------------------------------
#define READ_A(Q)                                                           \
  short8 aa0[2], aa1[2];                                                    \
  {                                                                         \
    const int r0 = (wr * 128 + ((Q) * 2 + 0) * 16 + fr) * 64;               \
    const int r1 = (wr * 128 + ((Q) * 2 + 1) * 16 + fr) * 64;               \
    aa0[0] = *(const short8*)&sA[c][r0 + ((0 + sl) ^ sx) * 8];              \
    aa0[1] = *(const short8*)&sA[c][r0 + ((4 + sl) ^ sx) * 8];              \
    aa1[0] = *(const short8*)&sA[c][r1 + ((0 + sl) ^ sx) * 8];              \
    aa1[1] = *(const short8*)&sA[c][r1 + ((4 + sl) ^ sx) * 8];              \
  }

#define PHASE_TAIL(Q)                                                       \
  __builtin_amdgcn_s_barrier();                                             \
  asm volatile("s_waitcnt lgkmcnt(0)" ::: "memory");                        \
  __builtin_amdgcn_s_setprio(1);                                            \
  _Pragma("unroll")                                                         \
  for (int kk = 0; kk < 2; ++kk) {                                          \
    _Pragma("unroll")                                                       \
    for (int ni = 0; ni < 4; ++ni) {                                        \
      acc[(Q) * 2 + 0][ni] = __builtin_amdgcn_mfma_f32_16x16x32_bf16(       \
          aa0[kk], b[ni][kk], acc[(Q) * 2 + 0][ni], 0, 0, 0);               \
      acc[(Q) * 2 + 1][ni] = __builtin_amdgcn_mfma_f32_16x16x32_bf16(       \
          aa1[kk], b[ni][kk], acc[(Q) * 2 + 1][ni], 0, 0, 0);               \
    }                                                                       \
  }                                                                         \
  __builtin_amdgcn_s_setprio(0);                                            \
  __builtin_amdgcn_s_barrier();

template <int MODE>
__global__ __launch_bounds__(512, 2) void gemm8_k(
    const u16* __restrict__ X, const u16* __restrict__ W,
    const float* __restrict__ bias, const float* __restrict__ resid,
    float* __restrict__ outf, u16* __restrict__ O) {
  __shared__ __align__(16) u16 sA[2][256 * 64];
  __shared__ __align__(16) u16 sB[2][256 * 64];
  const int tid = threadIdx.x;
  const int lane = tid & 63, wave = tid >> 6;
  const int wr = wave >> 2, wc = wave & 3;

  // XCD-aware bijective swizzle of the 256 blocks (8 XCDs x 32)
  const int flat = blockIdx.y * 64 + blockIdx.x;
  const int fl2 = (flat & 7) * 32 + (flat >> 3);
  const int row0 = (fl2 & 63) * 256;
  const int col0 = (fl2 >> 6) * 256;

  const int srow = tid >> 3;                       // 0..63
  const int lslot = ((tid & 7) ^ (srow & 7)) * 8;  // pre-swizzled source slot
  const int fr = lane & 15, sl = lane >> 4, sx = lane & 7;

  f32x4 acc[8][4];
#pragma unroll
  for (int i = 0; i < 8; ++i)
#pragma unroll
    for (int j = 0; j < 4; ++j) acc[i][j] = {0.f, 0.f, 0.f, 0.f};

  auto xbase = [](int s) {
    return s < 17 ? s * 64 : (s < 34 ? (s - 17) * 64 : KP + (s - 34) * 64);
  };
  auto stX = [&](int buf, int s, int i) {
    gld16(X + (size_t)(row0 + i * 64 + srow) * KX + xbase(s) + lslot,
          &sA[buf][i * 4096 + wave * 512]);
  };
  auto stW = [&](int buf, int s, int i) {
    gld16(W + (size_t)(col0 + i * 64 + srow) * KC + s * 64 + lslot,
          &sB[buf][i * 4096 + wave * 512]);
  };

  // prologue: T0 fully (8 issues), T1's first 6 (B0-3, A0, A2)
#pragma unroll
  for (int i = 0; i < 4; ++i) stX(0, 0, i);
#pragma unroll
  for (int i = 0; i < 4; ++i) stW(0, 0, i);
#pragma unroll
  for (int i = 0; i < 4; ++i) stW(1, 1, i);
  stX(1, 1, 0);
  stX(1, 1, 2);
  asm volatile("s_waitcnt vmcnt(6)" ::: "memory");
  __builtin_amdgcn_s_barrier();

  for (int t = 0; t < NSTEP; ++t) {
    const int c = t & 1;
    const bool h1 = (t + 1 < NSTEP), h2 = (t + 2 < NSTEP);
    // B for the whole tile (held across phases)
    short8 b[4][2];
#pragma unroll
    for (int ni = 0; ni < 4; ++ni) {
      const int row = (wc * 64 + ni * 16 + fr) * 64;
#pragma unroll
      for (int kk = 0; kk < 2; ++kk)
        b[ni][kk] = *(const short8*)&sB[c][row + ((kk * 4 + sl) ^ sx) * 8];
    }
    {  // phase 0: + stage T_{t+1} A1, A3 (other buffer; fully freed)
      READ_A(0)
      if (h1) { stX(c ^ 1, t + 1, 1); stX(c ^ 1, t + 1, 3); }
      PHASE_TAIL(0)
    }
    {  // phase 1: + stage T_{t+2} B0, B1 (cur buffer; B freed after P0)
      READ_A(1)
      if (h2) { stW(c, t + 2, 0); stW(c, t + 2, 1); }
      PHASE_TAIL(1)
    }
    {  // phase 2: + stage T_{t+2} B2, B3, A0 (A0 freed after P1)
      READ_A(2)
      if (h2) { stW(c, t + 2, 2); stW(c, t + 2, 3); stX(c, t + 2, 0); }
      PHASE_TAIL(2)
    }
    {  // phase 3: + stage T_{t+2} A2; counted wait for T_{t+1}
      READ_A(3)
      if (h2) {
        stX(c, t + 2, 2);
        asm volatile("s_waitcnt vmcnt(6)" ::: "memory");
      } else if (h1) {
        asm volatile("s_waitcnt vmcnt(0)" ::: "memory");
      }
      PHASE_TAIL(3)
    }
  }

  // epilogue (C/D: col = lane&15, row = (lane>>4)*4 + reg)
  const int crow0 = row0 + wr * 128 + (lane >> 4) * 4;
  const int ccolb = col0 + wc * 64 + fr;
#pragma unroll
  for (int ni = 0; ni < 4; ++ni) {
    const int col = ccolb + ni * 16;
    const float bvv = bias[col];
#pragma unroll
    for (int mi = 0; mi < 8; ++mi) {
#pragma unroll
      for (int r = 0; r < 4; ++r) {
        const int rw = crow0 + mi * 16 + r;
        float v = acc[mi][ni][r] + bvv;
        if (MODE == 0) {
          v = fmaxf(v, 0.f);
          u16 h, l; split_bf(v, h, l);
          O[(size_t)rw * KX + col] = h;
          O[(size_t)rw * KX + KP + col] = l;
        } else {
          v += resid[(size_t)rw * DIM + col];
          outf[(size_t)rw * DIM + col] = v;
        }
      }
    }
  }
}

// ---------------------------------------------------------------------------
// LayerNorm row kernel -> fp32 resid + split act out (stride KX)
// ---------------------------------------------------------------------------
__global__ __launch_bounds__(256) void ln_k(
    const float* __restrict__ y, const float* __restrict__ g,
    const float* __restrict__ b, float* __restrict__ ro, u16* __restrict__ O) {
  const int row = blockIdx.x, tid = threadIdx.x;
  const int lane = tid & 63, wave = tid >> 6;
  __shared__ float r1[4], r2[4];
  const float4 v = ((const float4*)(y + (size_t)row * DIM))[tid];
  float s = v.x + v.y + v.z + v.w;
#pragma unroll
  for (int o = 32; o > 0; o >>= 1) s += __shfl_down(s, o);
  if (lane == 0) r1[wave] = s;
  __syncthreads();
  const float mean = (r1[0] + r1[1] + r1[2] + r1[3]) * (1.0f / DIM);
  const float d0 = v.x - mean, d1 = v.y - mean, d2 = v.z - mean, d3 = v.w - mean;
  float q = d0 * d0 + d1 * d1 + d2 * d2 + d3 * d3;
#pragma unroll
  for (int o = 32; o > 0; o >>= 1) q += __shfl_down(q, o);
  if (lane == 0) r2[wave] = q;
  __syncthreads();
  const float var = (r2[0] + r2[1] + r2[2] + r2[3]) * (1.0f / DIM);
  const float rs = rsqrtf(var + 1e-5f);
  const float4 gv = ((const float4*)g)[tid];
  const float4 bv = ((const float4*)b)[tid];
  const float o0 = d0 * rs * gv.x + bv.x;
  const float o1 = d1 * rs * gv.y + bv.y;
  const float o2 = d2 * rs * gv.z + bv.z;
  const float o3 = d3 * rs * gv.w + bv.w;
  ((float4*)(ro + (size_t)row * DIM))[tid] = make_float4(o0, o1, o2, o3);
  u16 h0, l0, h1, l1, h2, l2, h3, l3;
  split_bf(o0, h0, l0); split_bf(o1, h1, l1);
  split_bf(o2, h2, l2); split_bf(o3, h3, l3);
  ushort4 hh; hh.x = h0; hh.y = h1; hh.z = h2; hh.w = h3;
  ushort4 ll; ll.x = l0; ll.y = l1; ll.z = l2; ll.w = l3;
  *(ushort4*)&O[(size_t)row * KX + tid * 4] = hh;
  *(ushort4*)&O[(size_t)row * KX + KP + tid * 4] = ll;
}

// ---------------------------------------------------------------------------
extern "C" void kernel_launch(void* const* d_in, const int* in_sizes, int n_in,
                              void* d_out, int out_size, void* d_ws, size_t ws_size,
                              hipStream_t stream) {
  const float* x      = (const float*)d_in[0];
  const int*   qw     = (const int*)d_in[1];
  const float* scales = (const float*)d_in[2];
  const float* bias   = (const float*)d_in[3];
  const float* lora_A = (const float*)d_in[4];
  const float* lora_B = (const float*)d_in[5];
  const float* ln_g   = (const float*)d_in[6];
  const float* ln_b   = (const float*)d_in[7];

  char* p = (char*)d_ws;
  auto carve = [&](size_t bytes) {
    char* r = p;
    p += (bytes + 255) & ~(size_t)255;
    return (void*)r;
  };
  // ws ~ 219 MB: Wc 6.7 + Ac 2.5 + acts 142.6 + residb 67.1
  u16* Wc  = (u16*)carve((size_t)1024 * KC * 2);     // one-layer ring
  u16* Ac  = (u16*)carve((size_t)NLIN * RLORA * KX * 2);
  u16* aA  = (u16*)carve((size_t)NTOK * KX * 2);
  u16* aB  = (u16*)carve((size_t)NTOK * KX * 2);
  float* residb = (float*)carve((size_t)NTOK * DIM * 4);
  float* ybuf   = (float*)d_out;

  {
    const int tot = NLIN * RLORA * (KX / 16);
    pack_a_k<<<(tot + 255) / 256, 256, 0, stream>>>(lora_A, Ac);
  }
  {
    const int tot = NTOK * 68;
    pack_x_k<<<(tot + 255) / 256, 256, 0, stream>>>(x, aA, aB);
  }

  u16 *inA = aA, *outA = aB;
  const float* resid = x;
  const int wtot = 1024 * (KC / 16);
  dim3 grid(64, 4);
  for (int blk = 0; blk < NBLK; ++blk) {
    for (int j = 0; j < 3; ++j) {
      const int li = 3 * blk + j;
      pack_w_k<<<(wtot + 255) / 256, 256, 0, stream>>>(
          qw + (size_t)li * DIM * DIM, scales + (size_t)li * DIM * (DIM / 16),
          lora_B + (size_t)li * DIM * RLORA, Wc);
      t_k<<<NTOK / 128, 256, 0, stream>>>(inA, Ac + (size_t)li * RLORA * KX);
      const float* lb = bias + (size_t)li * DIM;
      if (j < 2) {
        gemm8_k<0><<<grid, 512, 0, stream>>>(inA, Wc, lb, nullptr, nullptr, outA);
        u16* tswp = inA; inA = outA; outA = tswp;
      } else {
        gemm8_k<1><<<grid, 512, 0, stream>>>(inA, Wc, lb, resid, ybuf, nullptr);
        if (blk < NBLK - 1) {
          ln_k<<<NTOK, 256, 0, stream>>>(ybuf, ln_g + (size_t)blk * DIM,
                                         ln_b + (size_t)blk * DIM, residb, outA);
          resid = residb;
          u16* tswp = inA; inA = outA; outA = tswp;
        }
      }
    }
  }
  (void)in_sizes; (void)n_in; (void)out_size; (void)ws_size;
}

// Round 5
// 2886.578 us; speedup vs baseline: 1.2749x; 1.2749x over previous
//
#include <hip/hip_runtime.h>
#include <cstdint>

// ---------------------------------------------------------------------------
// QLoRABigNet. R2-proven split-bf16 GEMM (128x128, 2-phase __syncthreads,
// gld_lds 16B, XOR slot swizzle) + explicit XCD row-panel grouping (bijective).
// t_k: R2 sync structure (single buffer, __syncthreads full-drain), 64-row
// blocks, hi-only x staging (t = xh @ (Ah+Al)^T, validated in R3).
// ---------------------------------------------------------------------------

#define NTOK 16384
#define DIM  1024
#define KP   1088     // augmented+padded K (1024 base + 32 lora + 32 zero)
#define RLORA 32
#define NLIN 18
#define NBLK 6

typedef unsigned short u16;
typedef __attribute__((ext_vector_type(8))) short short8;
typedef __attribute__((ext_vector_type(4))) float f32x4;

__device__ __forceinline__ u16 f2bf(float f) {
  uint32_t u = __float_as_uint(f);
  u += 0x7fffu + ((u >> 16) & 1u);          // round-to-nearest-even
  return (u16)(u >> 16);
}
__device__ __forceinline__ float bf2f(u16 h) {
  return __uint_as_float(((uint32_t)h) << 16);
}
__device__ __forceinline__ void split_bf(float f, u16& h, u16& l) {
  h = f2bf(f);
  l = f2bf(f - bf2f(h));                    // exact residual
}

__device__ __forceinline__ void gld16(const void* g, void* lds) {
  __builtin_amdgcn_global_load_lds(
      (const __attribute__((address_space(1))) uint32_t*)g,
      (__attribute__((address_space(3))) uint32_t*)lds, 16, 0, 0);
}

// ---------------------------------------------------------------------------
// Pack kernels (unchanged from R2)
// ---------------------------------------------------------------------------

// One layer: Wa[o][0:1024]=dequant(q,s); [1024:1056]=lora_B[o][:]; rest 0
__global__ void pack_w_k(const int* __restrict__ qw, const float* __restrict__ sc,
                         const float* __restrict__ lb,
                         u16* __restrict__ Wh, u16* __restrict__ Wl) {
  const int idx = blockIdx.x * 256 + threadIdx.x;
  if (idx >= 1024 * (KP / 16)) return;
  const int g = idx % (KP / 16);
  const int o = idx / (KP / 16);
  u16 h[16], l[16];
  if (g < 64) {
    const int* q = qw + (size_t)o * 1024 + g * 16;
    const float s = sc[(size_t)o * 64 + g];
#pragma unroll
    for (int j = 0; j < 16; ++j) {
      float w = ((float)q[j] * (2.0f / 15.0f) - 1.0f) * s;
      split_bf(w, h[j], l[j]);
    }
  } else if (g < 66) {
    const float* B = lb + (size_t)o * RLORA + (g - 64) * 16;
#pragma unroll
    for (int j = 0; j < 16; ++j) split_bf(B[j], h[j], l[j]);
  } else {
#pragma unroll
    for (int j = 0; j < 16; ++j) { h[j] = 0; l[j] = 0; }
  }
  u16* wh = Wh + (size_t)o * KP + g * 16;
  u16* wl = Wl + (size_t)o * KP + g * 16;
#pragma unroll
  for (int j = 0; j < 16; ++j) { wh[j] = h[j]; wl[j] = l[j]; }
}

// Aa[li][r][0:1024]=lora_A (split); rest 0  (all 18 layers)
__global__ void pack_a_k(const float* __restrict__ la,
                         u16* __restrict__ Ah, u16* __restrict__ Al) {
  const int idx = blockIdx.x * 256 + threadIdx.x;
  if (idx >= NLIN * RLORA * (KP / 16)) return;
  const int g = idx % (KP / 16);
  const int rem = idx / (KP / 16);
  u16 h[16], l[16];
  if (g < 64) {
    const float* a = la + (size_t)rem * 1024 + g * 16;
#pragma unroll
    for (int j = 0; j < 16; ++j) split_bf(a[j], h[j], l[j]);
  } else {
#pragma unroll
    for (int j = 0; j < 16; ++j) { h[j] = 0; l[j] = 0; }
  }
  u16* ph = Ah + (size_t)rem * KP + g * 16;
  u16* pl = Al + (size_t)rem * KP + g * 16;
#pragma unroll
  for (int j = 0; j < 16; ++j) { ph[j] = h[j]; pl[j] = l[j]; }
}

// acts: split(x) into hi/lo; pad cols (>=1024) of BOTH act buffer pairs zeroed.
__global__ void pack_x_k(const float* __restrict__ x,
                         u16* __restrict__ aAh, u16* __restrict__ aAl,
                         u16* __restrict__ aBh, u16* __restrict__ aBl) {
  const int idx = blockIdx.x * 256 + threadIdx.x;
  if (idx >= NTOK * (KP / 16)) return;
  const int g = idx % (KP / 16);
  const int n = idx / (KP / 16);
  const size_t dofs = (size_t)n * KP + g * 16;
  if (g < 64) {
    const float* xp = x + (size_t)n * DIM + g * 16;
#pragma unroll
    for (int j = 0; j < 16; ++j) {
      u16 h, l;
      split_bf(xp[j], h, l);
      aAh[dofs + j] = h; aAl[dofs + j] = l;
    }
  } else {
#pragma unroll
    for (int j = 0; j < 16; ++j) {
      aAh[dofs + j] = 0; aAl[dofs + j] = 0;
      aBh[dofs + j] = 0; aBl[dofs + j] = 0;
    }
  }
}

// ---------------------------------------------------------------------------
// t_k: t = xh @ (Ah+Al)^T -> Xh cols [1024:1056) (hi only; Xl t-cols stay
// zero from pack_x). 256 blocks x 64 rows, 4 waves, R2-proven sync:
// stage -> __syncthreads (full vmcnt drain) -> compute -> __syncthreads.
// ---------------------------------------------------------------------------
__global__ __launch_bounds__(256, 4) void t_k(
    u16* __restrict__ Xh, const u16* __restrict__ LAh,
    const u16* __restrict__ LAl) {
  __shared__ __align__(16) u16 sX[64 * 64];
  const int tid = threadIdx.x, lane = tid & 63, wave = tid >> 6;
  const int row0 = blockIdx.x * 64;
  const int fr = lane & 15, sl = lane >> 4;
  const int xr = tid >> 3, xs = tid & 7;   // stage row (0..31), slot

  f32x4 acc[2];
  acc[0] = {0.f, 0.f, 0.f, 0.f};
  acc[1] = {0.f, 0.f, 0.f, 0.f};

  for (int t = 0; t < 16; ++t) {
    const int kofs = t * 64;
    // stage 64 rows x 64 cols of xh (two 32-row slabs), source slot-XOR'd
    gld16(Xh + (size_t)(row0 + xr) * KP + kofs + (xs ^ (xr & 7)) * 8,
          &sX[tid * 8]);
    gld16(Xh + (size_t)(row0 + 32 + xr) * KP + kofs + (xs ^ (xr & 7)) * 8,
          &sX[2048 + tid * 8]);
    __syncthreads();                       // full drain: all staging visible
    short8 a[2];
#pragma unroll
    for (int kk = 0; kk < 2; ++kk) {
      const int arow = wave * 16 + fr;
      a[kk] = *(const short8*)&sX[arow * 64 + (((kk * 4 + sl) ^ (fr & 7))) * 8];
    }
#pragma unroll
    for (int n = 0; n < 2; ++n) {
      const int ar = n * 16 + fr;
#pragma unroll
      for (int kk = 0; kk < 2; ++kk) {
        const int ac = kofs + kk * 32 + sl * 8;
        short8 bh = *(const short8*)&LAh[(size_t)ar * KP + ac];
        short8 bl = *(const short8*)&LAl[(size_t)ar * KP + ac];
        acc[n] = __builtin_amdgcn_mfma_f32_16x16x32_bf16(a[kk], bh, acc[n], 0, 0, 0);
        acc[n] = __builtin_amdgcn_mfma_f32_16x16x32_bf16(a[kk], bl, acc[n], 0, 0, 0);
      }
    }
    __syncthreads();                       // WAR: reads done before next stage
  }
  // C/D: col = lane&15, row = (lane>>4)*4 + reg
  const int crow0 = row0 + wave * 16 + (lane >> 4) * 4;
#pragma unroll
  for (int n = 0; n < 2; ++n) {
    const int col = DIM + n * 16 + fr;
#pragma unroll
    for (int r = 0; r < 4; ++r)
      Xh[(size_t)(crow0 + r) * KP + col] = f2bf(acc[n][r]);
  }
}

// ---------------------------------------------------------------------------
// Main GEMM (R2-proven body): 128x128 tile, BK=64, 4 waves.
// Block mapping: XCD k owns row-panels [k*16,(k+1)*16) x all 8 col-panels
// (bijective; matches measured-de-facto round-robin XCD assignment).
// MODE 0: relu -> split act out. MODE 1: +resid -> fp32 out.
// ---------------------------------------------------------------------------
template <int MODE>
__global__ __launch_bounds__(256, 2) void gemm_k(
    const u16* __restrict__ Xh, const u16* __restrict__ Xl,
    const u16* __restrict__ Wh, const u16* __restrict__ Wl,
    const float* __restrict__ bias, const float* __restrict__ resid,
    float* __restrict__ outf, u16* __restrict__ Oh, u16* __restrict__ Ol) {
  __shared__ __align__(16) u16 sXh[128 * 64], sXl[128 * 64];
  __shared__ __align__(16) u16 sWh[128 * 64], sWl[128 * 64];
  const int tid = threadIdx.x;
  const int lane = tid & 63, wave = tid >> 6;
  const int wr = wave >> 1, wc = wave & 1;

  const int flat = blockIdx.y * 128 + blockIdx.x;
  const int xcd = flat & 7, idx = flat >> 3;
  const int row0 = (xcd * 16 + (idx >> 3)) * 128;
  const int col0 = (idx & 7) * 128;

  f32x4 acc[4][4];
#pragma unroll
  for (int i = 0; i < 4; ++i)
#pragma unroll
    for (int j = 0; j < 4; ++j) acc[i][j] = {0.f, 0.f, 0.f, 0.f};

  const int sr = tid >> 3;
  const int ss = ((tid & 7) ^ (sr & 7)) * 8;
  const size_t xoff = (size_t)(row0 + sr) * KP + ss;
  const size_t woff = (size_t)(col0 + sr) * KP + ss;

  const int arow = wr * 64 + (lane & 15);
  const int brow = wc * 64 + (lane & 15);
  const int sl = lane >> 4, sx = lane & 7;

  for (int ks = 0; ks < KP / 64; ++ks) {
    const int kofs = ks * 64;
#pragma unroll
    for (int r = 0; r < 4; ++r) {
      const size_t go = (size_t)(r * 32) * KP + kofs;
      const int lo = wave * 512 + r * 2048;
      gld16(Xh + xoff + go, &sXh[lo]);
      gld16(Xl + xoff + go, &sXl[lo]);
      gld16(Wh + woff + go, &sWh[lo]);
      gld16(Wl + woff + go, &sWl[lo]);
    }
    __syncthreads();
#pragma unroll
    for (int kk = 0; kk < 2; ++kk) {
      const int so = ((kk * 4 + sl) ^ sx) * 8;
      short8 ah[4], am[4], bh[4], bm[4];
#pragma unroll
      for (int mi = 0; mi < 4; ++mi) {
        const int off = (arow + mi * 16) * 64 + so;
        ah[mi] = *(const short8*)&sXh[off];
        am[mi] = *(const short8*)&sXl[off];
      }
#pragma unroll
      for (int ni = 0; ni < 4; ++ni) {
        const int off = (brow + ni * 16) * 64 + so;
        bh[ni] = *(const short8*)&sWh[off];
        bm[ni] = *(const short8*)&sWl[off];
      }
#pragma unroll
      for (int mi = 0; mi < 4; ++mi)
#pragma unroll
        for (int ni = 0; ni < 4; ++ni) {
          f32x4 c = acc[mi][ni];
          c = __builtin_amdgcn_mfma_f32_16x16x32_bf16(ah[mi], bm[ni], c, 0, 0, 0);
          c = __builtin_amdgcn_mfma_f32_16x16x32_bf16(am[mi], bh[ni], c, 0, 0, 0);
          c = __builtin_amdgcn_mfma_f32_16x16x32_bf16(ah[mi], bh[ni], c, 0, 0, 0);
          acc[mi][ni] = c;
        }
    }
    __syncthreads();
  }

  const int crow0 = row0 + wr * 64 + (lane >> 4) * 4;
  const int ccol0 = col0 + wc * 64 + (lane & 15);
#pragma unroll
  for (int ni = 0; ni < 4; ++ni) {
    const int col = ccol0 + ni * 16;
    const float bv = bias[col];
#pragma unroll
    for (int mi = 0; mi < 4; ++mi) {
#pragma unroll
      for (int r = 0; r < 4; ++r) {
        const int rw = crow0 + mi * 16 + r;
        float v = acc[mi][ni][r] + bv;
        if (MODE == 0) {
          v = fmaxf(v, 0.f);
          u16 h, l;
          split_bf(v, h, l);
          Oh[(size_t)rw * KP + col] = h;
          Ol[(size_t)rw * KP + col] = l;
        } else {
          v += resid[(size_t)rw * DIM + col];
          outf[(size_t)rw * DIM + col] = v;
        }
      }
    }
  }
}

// ---------------------------------------------------------------------------
// LayerNorm -> fp32 resid + split act out (unchanged from R2)
// ---------------------------------------------------------------------------
__global__ __launch_bounds__(256) void ln_k(
    const float* __restrict__ y, const float* __restrict__ g,
    const float* __restrict__ b, float* __restrict__ ro,
    u16* __restrict__ Oh, u16* __restrict__ Ol) {
  const int row = blockIdx.x, tid = threadIdx.x;
  const int lane = tid & 63, wave = tid >> 6;
  __shared__ float r1[4], r2[4];
  const float4 v = ((const float4*)(y + (size_t)row * DIM))[tid];
  float s = v.x + v.y + v.z + v.w;
#pragma unroll
  for (int o = 32; o > 0; o >>= 1) s += __shfl_down(s, o);
  if (lane == 0) r1[wave] = s;
  __syncthreads();
  const float mean = (r1[0] + r1[1] + r1[2] + r1[3]) * (1.0f / DIM);
  const float d0 = v.x - mean, d1 = v.y - mean, d2 = v.z - mean, d3 = v.w - mean;
  float q = d0 * d0 + d1 * d1 + d2 * d2 + d3 * d3;
#pragma unroll
  for (int o = 32; o > 0; o >>= 1) q += __shfl_down(q, o);
  if (lane == 0) r2[wave] = q;
  __syncthreads();
  const float var = (r2[0] + r2[1] + r2[2] + r2[3]) * (1.0f / DIM);
  const float rs = rsqrtf(var + 1e-5f);
  const float4 gv = ((const float4*)g)[tid];
  const float4 bv = ((const float4*)b)[tid];
  const float o0 = d0 * rs * gv.x + bv.x;
  const float o1 = d1 * rs * gv.y + bv.y;
  const float o2 = d2 * rs * gv.z + bv.z;
  const float o3 = d3 * rs * gv.w + bv.w;
  ((float4*)(ro + (size_t)row * DIM))[tid] = make_float4(o0, o1, o2, o3);
  u16 h0, l0, h1, l1, h2, l2, h3, l3;
  split_bf(o0, h0, l0); split_bf(o1, h1, l1);
  split_bf(o2, h2, l2); split_bf(o3, h3, l3);
  ushort4 hh; hh.x = h0; hh.y = h1; hh.z = h2; hh.w = h3;
  ushort4 ll; ll.x = l0; ll.y = l1; ll.z = l2; ll.w = l3;
  *(ushort4*)&Oh[(size_t)row * KP + tid * 4] = hh;
  *(ushort4*)&Ol[(size_t)row * KP + tid * 4] = ll;
}

// ---------------------------------------------------------------------------
extern "C" void kernel_launch(void* const* d_in, const int* in_sizes, int n_in,
                              void* d_out, int out_size, void* d_ws, size_t ws_size,
                              hipStream_t stream) {
  const float* x      = (const float*)d_in[0];
  const int*   qw     = (const int*)d_in[1];
  const float* scales = (const float*)d_in[2];
  const float* bias   = (const float*)d_in[3];
  const float* lora_A = (const float*)d_in[4];
  const float* lora_B = (const float*)d_in[5];
  const float* ln_g   = (const float*)d_in[6];
  const float* ln_b   = (const float*)d_in[7];

  char* p = (char*)d_ws;
  auto carve = [&](size_t bytes) {
    char* r = p;
    p += (bytes + 255) & ~(size_t)255;
    return (void*)r;
  };
  u16* Wh  = (u16*)carve((size_t)1024 * KP * 2);       // one-layer ring
  u16* Wl  = (u16*)carve((size_t)1024 * KP * 2);
  u16* Ah  = (u16*)carve((size_t)NLIN * RLORA * KP * 2);
  u16* Al  = (u16*)carve((size_t)NLIN * RLORA * KP * 2);
  u16* aAh = (u16*)carve((size_t)NTOK * KP * 2);
  u16* aAl = (u16*)carve((size_t)NTOK * KP * 2);
  u16* aBh = (u16*)carve((size_t)NTOK * KP * 2);
  u16* aBl = (u16*)carve((size_t)NTOK * KP * 2);
  float* residb = (float*)carve((size_t)NTOK * DIM * 4);
  float* ybuf   = (float*)d_out;                       // pre-LN sum in d_out

  {
    const int tot = NLIN * RLORA * (KP / 16);
    pack_a_k<<<(tot + 255) / 256, 256, 0, stream>>>(lora_A, Ah, Al);
  }
  {
    const int tot = NTOK * (KP / 16);
    pack_x_k<<<(tot + 255) / 256, 256, 0, stream>>>(x, aAh, aAl, aBh, aBl);
  }

  u16 *inH = aAh, *inL = aAl, *outH = aBh, *outL = aBl;
  const float* resid = x;
  const int wtot = 1024 * (KP / 16);
  for (int blk = 0; blk < NBLK; ++blk) {
    for (int j = 0; j < 3; ++j) {
      const int li = 3 * blk + j;
      pack_w_k<<<(wtot + 255) / 256, 256, 0, stream>>>(
          qw + (size_t)li * DIM * DIM, scales + (size_t)li * DIM * (DIM / 16),
          lora_B + (size_t)li * DIM * RLORA, Wh, Wl);
      t_k<<<NTOK / 64, 256, 0, stream>>>(
          inH, Ah + (size_t)li * RLORA * KP, Al + (size_t)li * RLORA * KP);
      const float* lb = bias + (size_t)li * DIM;
      dim3 grid(128, 8);
      if (j < 2) {
        gemm_k<0><<<grid, 256, 0, stream>>>(inH, inL, Wh, Wl, lb,
                                            nullptr, nullptr, outH, outL);
        u16* t;
        t = inH; inH = outH; outH = t;
        t = inL; inL = outL; outL = t;
      } else {
        gemm_k<1><<<grid, 256, 0, stream>>>(inH, inL, Wh, Wl, lb,
                                            resid, ybuf, nullptr, nullptr);
        if (blk < NBLK - 1) {
          ln_k<<<NTOK, 256, 0, stream>>>(ybuf, ln_g + (size_t)blk * DIM,
                                         ln_b + (size_t)blk * DIM, residb,
                                         outH, outL);
          resid = residb;
          u16* t;
          t = inH; inH = outH; outH = t;
          t = inL; inL = outL; outL = t;
        }
      }
    }
  }
  (void)in_sizes; (void)n_in; (void)out_size; (void)ws_size;
}